// Round 4
// baseline (215.308 us; speedup 1.0000x reference)
//
#include <hip/hip_runtime.h>

// KNN k-th smallest distance, two-pass threshold-filter MFMA version.
// dist = sqrt(2 - 2*dot(zn,rn)); sorted(dist)[k] == (k+1)-th LARGEST dot.
//  1) normalize_bf16: fused z+ref rows -> L2-normalized bf16
//  2) knn_pass<1>:  MFMA dots, epilogue = per-(row,chunk,lane16) subset MAX
//  3) knn_threshold: per row, exact 11th-largest of 1280 subset maxes -> T
//  4) knn_pass<2>:  MFMA dots again, keep v >= T[row] via atomic append
//  5) knn_final: exact 11th-largest of survivors -> dist
//
// Round-4 change (single variable): occupancy 3 -> 5 blocks/CU.
// Evidence: per-block-iteration rhythm is structural (~6100 cyc) and matches
// m97's verified GEMM structure exactly (2.45 vs 2.62 us/iter for identical
// per-iter MFLOP); m97's higher TF was residency (4 blocks/CU vs our 3).
// Shared-pipe headroom at 5 blocks/CU: LDS-read ~3840 cyc/slot, MFMA 800
// cyc/SIMD, staging 30 GB/s/CU -- none binds.  LDS 5 x 32 KB = 160 KB exact.
//  - NCH=80: grid 16x80=1280 blocks (5/CU), chunk=625 exactly (balanced),
//    nt=10.  1280%8==0 -> bijective XCD swizzle; per-XCD refs 1.6MB L2-fit.
//  - __launch_bounds__(256, 5); VGPR 68 fits the 102 cap.
//  - NSUB=1280; threshold does 20 sorted-insert rounds (round-3 rewrite).
//
// Accuracy: bf16 rounding perturbs each dot by ~3.5e-4; k-th order statistic
// is 1-Lipschitz in that perturbation -> << 2.39e-2 threshold.  Threshold
// bound: a subset max > v11 (true 11th-largest) implies the subset holds a
// top-10 dot -> at most 10 such subsets -> T (11th-largest subset max) <= v11,
// so all top-11 dots survive the v >= T filter.

#define D_DIM 128
#define TQ 128         // queries per block (4 waves x 2 row-tiles x 16 rows)
#define BR 64          // refs per block iteration
#define NCH 80         // ref chunks; grid 16*80=1280 blocks = 5/CU; 1280%8==0
#define NSUB (NCH * 16) // subsets per row = 1280
#define KK 11          // need 11th largest (k=10); selection slots
#define CAP 256        // survivor capacity per row

typedef __bf16 bf16_t;
typedef bf16_t bf16x8 __attribute__((ext_vector_type(8)));
typedef float f32x4 __attribute__((ext_vector_type(4)));

__device__ __forceinline__ unsigned short f2bf(float f) {
    unsigned u = __float_as_uint(f);
    return (unsigned short)((u + 0x7fffu + ((u >> 16) & 1u)) >> 16);  // RNE
}

__global__ __launch_bounds__(256) void normalize_bf16(
    const float* __restrict__ z, const float* __restrict__ ref,
    unsigned short* __restrict__ zb, unsigned short* __restrict__ rb,
    int N, int M)
{
    const int w = threadIdx.x >> 6;
    const int l = threadIdx.x & 63;
    const int row = blockIdx.x * 4 + w;
    if (row >= N + M) return;
    const float* in; unsigned short* out; int r;
    if (row < N) { in = z;   out = zb; r = row; }
    else         { in = ref; out = rb; r = row - N; }
    const float2 v = ((const float2*)in)[(size_t)r * 64 + l];
    float ss = v.x * v.x + v.y * v.y;
    #pragma unroll
    for (int off = 32; off > 0; off >>= 1) ss += __shfl_xor(ss, off);
    const float inv = rsqrtf(ss);
    ushort2 o; o.x = f2bf(v.x * inv); o.y = f2bf(v.y * inv);
    ((ushort2*)out)[(size_t)r * 64 + l] = o;
}

// async global->LDS, 16B per lane; LDS dest is wave-uniform base + lane*16.
__device__ __forceinline__ void gld_lds16(const unsigned short* g,
                                          unsigned short* l) {
    __builtin_amdgcn_global_load_lds(
        (__attribute__((address_space(1))) void*)g,
        (__attribute__((address_space(3))) void*)l, 16, 0, 0);
}

// PASS==1: write subset maxes.  PASS==2: filter vs T, append survivors.
template <int PASS>
__global__ __launch_bounds__(256, 5) void knn_pass(
    const unsigned short* __restrict__ zb, const unsigned short* __restrict__ rb,
    float* __restrict__ maxes, const float* __restrict__ T,
    int* __restrict__ cnt, float* __restrict__ surv,
    int N, int M, int chunk)
{
    // Double-buffered B tile: 2 x 64 rows x 128 bf16 (256B/row, no pad;
    // bank spread comes from the XOR slot swizzle).  32 KiB total.
    __shared__ __align__(16) unsigned short Bt[2 * BR * D_DIM];

    // T1 XCD swizzle: dispatch round-robins linear bid over 8 XCDs.  Remap so
    // XCD k owns ref-chunks [10k, 10k+10) exclusively (1.6 MB, L2-fit).
    const int nbx = (int)gridDim.x;                       // 16
    const int nwg = nbx * (int)gridDim.y;                 // 1280, %8 == 0
    const int bid = (int)blockIdx.x + nbx * (int)blockIdx.y;
    const int swz = (bid & 7) * (nwg >> 3) + (bid >> 3);
    const int bx = swz % nbx;
    const int by = swz / nbx;

    const int t = threadIdx.x;
    const int lane = t & 63;
    const int w = t >> 6;          // wave -> query rows w*32 .. w*32+31
    const int quad = lane >> 4;
    const int ln = lane & 15;
    const int qbase = bx * TQ;
    const int c0 = by * chunk;
    const int c1 = min(c0 + chunk, M);
    const int nt = (c1 - c0 + BR - 1) / BR;   // block-uniform (10 here)

    // A fragments straight from global: rows w*32 + rt*16 + ln, loop-invariant.
    // zb is 0.5 MB -> L2-resident; one-time cost.
    bf16x8 afr[2][4];
    #pragma unroll
    for (int rt = 0; rt < 2; ++rt)
        #pragma unroll
        for (int ks = 0; ks < 4; ++ks)
            afr[rt][ks] = *(const bf16x8*)
                &zb[(size_t)(qbase + w * 32 + rt * 16 + ln) * D_DIM
                    + ks * 32 + quad * 8];

    float mx[2][4];   // pass1: per-lane subset max, rows rt*16+quad*4+r
    float tr[2][4];   // pass2: per-row thresholds
    if (PASS == 1) {
        #pragma unroll
        for (int rt = 0; rt < 2; ++rt)
            #pragma unroll
            for (int r = 0; r < 4; ++r) mx[rt][r] = -3.0f;
    } else {
        #pragma unroll
        for (int rt = 0; rt < 2; ++rt)
            #pragma unroll
            for (int r = 0; r < 4; ++r)
                tr[rt][r] = T[qbase + w * 32 + rt * 16 + quad * 4 + r];
    }

    // Stage one 64-row tile into LDS half `half`.  Per wave: 4 glds calls,
    // each 4 rows (64 lanes x 16B = 1KB, linear dest).  Source slot is
    // pre-swizzled so LDS row r physical slot p holds logical slot p^(r&15).
    auto stage = [&](int half, int tile) {
        const int s0 = c0 + tile * BR;
        #pragma unroll
        for (int i = 0; i < 4; ++i) {
            const int r = w * 16 + i * 4 + quad;        // lane's source row
            int g = s0 + r; if (g > M - 1) g = M - 1;   // clamp; excluded below
            const int sl = ln ^ (r & 15);               // inverse-swizzled slot
            gld_lds16(&rb[(size_t)g * D_DIM + sl * 8],
                      &Bt[half * (BR * D_DIM) + (w * 16 + i * 4) * D_DIM]);
        }
    };

    stage(0, 0);
    stage(1, nt > 1 ? 1 : 0);

    for (int it = 0; it < nt; ++it) {
        // Wait only for THIS tile's 4 stage loads (tile it+1's 4 stay in
        // flight).  Last iteration has no younger stage group -> drain.
        if (it + 1 < nt) asm volatile("s_waitcnt vmcnt(4)" ::: "memory");
        else             asm volatile("s_waitcnt vmcnt(0)" ::: "memory");
        __builtin_amdgcn_s_barrier();
        asm volatile("" ::: "memory");        // no LDS reads hoisted above
        __builtin_amdgcn_sched_barrier(0);

        const int cur = it & 1;
        const int s0 = c0 + it * BR;
        const unsigned short* Bc = &Bt[cur * (BR * D_DIM)];

        f32x4 acc[2][4];
        #pragma unroll
        for (int rt = 0; rt < 2; ++rt)
            #pragma unroll
            for (int ct = 0; ct < 4; ++ct) acc[rt][ct] = (f32x4){0.f,0.f,0.f,0.f};

        __builtin_amdgcn_s_setprio(1);
        #pragma unroll
        for (int ks = 0; ks < 4; ++ks) {
            #pragma unroll
            for (int ct = 0; ct < 4; ++ct) {
                const int r = ct * 16 + ln;
                bf16x8 bfr = *(const bf16x8*)
                    &Bc[r * D_DIM + ((ks * 4 + quad) ^ ln) * 8];  // swizzled read
                #pragma unroll
                for (int rt = 0; rt < 2; ++rt)
                    acc[rt][ct] = __builtin_amdgcn_mfma_f32_16x16x32_bf16(
                        afr[rt][ks], bfr, acc[rt][ct], 0, 0, 0);
            }
        }
        __builtin_amdgcn_s_setprio(0);

        // Epilogue. Lane's column g is uniform across rt/r for fixed ct.
        #pragma unroll
        for (int ct = 0; ct < 4; ++ct) {
            int g = s0 + ct * 16 + ln;
            if (g < c1) {
                if (PASS == 1) {
                    #pragma unroll
                    for (int rt = 0; rt < 2; ++rt)
                        #pragma unroll
                        for (int r = 0; r < 4; ++r)
                            mx[rt][r] = fmaxf(mx[rt][r], acc[rt][ct][r]);
                } else {
                    #pragma unroll
                    for (int rt = 0; rt < 2; ++rt)
                        #pragma unroll
                        for (int r = 0; r < 4; ++r) {
                            float v = acc[rt][ct][r];
                            if (v >= tr[rt][r]) {   // rare
                                int row = qbase + w * 32 + rt * 16 + quad * 4 + r;
                                int slot = atomicAdd(&cnt[row], 1);
                                if (slot < CAP) surv[(size_t)row * CAP + slot] = v;
                            }
                        }
                }
            }
        }

        __builtin_amdgcn_sched_barrier(0);
        asm volatile("" ::: "memory");        // no LDS reads sunk below
        __builtin_amdgcn_s_barrier();          // all waves done reading buf[cur]
        if (it + 2 < nt) stage(cur, it + 2);   // refill the buffer just read
    }

    if (PASS == 1) {
        #pragma unroll
        for (int rt = 0; rt < 2; ++rt)
            #pragma unroll
            for (int r = 0; r < 4; ++r) {
                int row = qbase + w * 32 + rt * 16 + quad * 4 + r;
                maxes[(size_t)row * NSUB + by * 16 + ln] = mx[rt][r];
            }
    }
}

// Per-lane sorted top-(KK) slots, then kk+1 global max-extractions with
// static-shift pop (rule #20: no dynamic register indexing).
__device__ __forceinline__ float kth_largest_64(float* s, int kk, int t) {
    float cur = -3.0f;
    for (int it = 0; it <= kk; ++it) {
        float m = s[0];
        #pragma unroll
        for (int off = 32; off > 0; off >>= 1) m = fmaxf(m, __shfl_xor(m, off));
        cur = m;
        unsigned long long b = __ballot(s[0] == m);
        bool owner = ((int)(__ffsll(b) - 1) == t);
        #pragma unroll
        for (int j = 0; j < KK - 1; ++j) s[j] = owner ? s[j + 1] : s[j];
        if (owner) s[KK - 1] = -3.0f;
    }
    return cur;
}

__global__ __launch_bounds__(64) void knn_threshold(
    const float* __restrict__ maxes, const int* __restrict__ kp,
    float* __restrict__ T, int* __restrict__ cnt)
{
    const int row = blockIdx.x;
    const int t = threadIdx.x;
    float s[KK];
    #pragma unroll
    for (int j = 0; j < KK; ++j) s[j] = -3.0f;
    #pragma unroll
    for (int i = 0; i < NSUB / 64; ++i) {     // 20 coalesced loads
        float v = maxes[(size_t)row * NSUB + t + 64 * i];
        #pragma unroll
        for (int j = 0; j < KK; ++j) {        // descending sorted insert
            float hi = fmaxf(s[j], v), lo = fminf(s[j], v);
            s[j] = hi; v = lo;
        }
    }
    const int kk = *kp;   // 10
    float cur = kth_largest_64(s, kk, t);
    if (t == 0) { T[row] = cur; cnt[row] = 0; }
}

__global__ __launch_bounds__(64) void knn_final(
    const float* __restrict__ surv, const int* __restrict__ cnt,
    const int* __restrict__ kp, float* __restrict__ out)
{
    const int row = blockIdx.x;
    const int t = threadIdx.x;
    int c = cnt[row]; if (c > CAP) c = CAP;
    float s[KK];
    #pragma unroll
    for (int j = 0; j < KK; ++j) s[j] = -3.0f;
    #pragma unroll
    for (int i = 0; i < CAP / 64; ++i) {      // 4 coalesced loads
        int idx = t + 64 * i;
        float v = (idx < c) ? surv[(size_t)row * CAP + idx] : -3.0f;
        #pragma unroll
        for (int j = 0; j < KK; ++j) {
            float hi = fmaxf(s[j], v), lo = fminf(s[j], v);
            s[j] = hi; v = lo;
        }
    }
    const int kk = *kp;
    float cur = kth_largest_64(s, kk, t);
    if (t == 0) out[row] = sqrtf(fmaxf(2.0f - 2.0f * cur, 1e-12f));
}

extern "C" void kernel_launch(void* const* d_in, const int* in_sizes, int n_in,
                              void* d_out, int out_size, void* d_ws, size_t ws_size,
                              hipStream_t stream) {
    const float* z   = (const float*)d_in[0];
    const float* ref = (const float*)d_in[1];
    const int*   kp  = (const int*)d_in[2];
    float* out = (float*)d_out;

    const int N = in_sizes[0] / D_DIM;   // 2048
    const int M = in_sizes[1] / D_DIM;   // 50000

    unsigned short* zbuf = (unsigned short*)d_ws;             // N*128 bf16
    unsigned short* rbuf = zbuf + (size_t)N * D_DIM;          // M*128 bf16
    float* maxes = (float*)(rbuf + (size_t)M * D_DIM);        // N*NSUB f32 (10.5MB)
    float* T     = maxes + (size_t)N * NSUB;                  // N f32
    int*   cnt   = (int*)(T + N);                             // N i32
    float* surv  = (float*)(cnt + N);                         // N*CAP f32 (2MB)

    normalize_bf16<<<(N + M + 3) / 4, 256, 0, stream>>>(z, ref, zbuf, rbuf, N, M);

    const int chunk = (M + NCH - 1) / NCH;    // 625 (exactly balanced)
    dim3 grid(N / TQ, NCH);                   // 16 x 80 = 1280 blocks, 5/CU

    knn_pass<1><<<grid, 256, 0, stream>>>(zbuf, rbuf, maxes, nullptr,
                                          nullptr, nullptr, N, M, chunk);
    knn_threshold<<<N, 64, 0, stream>>>(maxes, kp, T, cnt);
    knn_pass<2><<<grid, 256, 0, stream>>>(zbuf, rbuf, nullptr, T,
                                          cnt, surv, N, M, chunk);
    knn_final<<<N, 64, 0, stream>>>(surv, cnt, kp, out);
}

// Round 5
// 158.580 us; speedup vs baseline: 1.3577x; 1.3577x over previous
//
#include <hip/hip_runtime.h>

// KNN k-th smallest distance, two-pass threshold-filter MFMA version.
// dist = sqrt(2 - 2*dot(zn,rn)); sorted(dist)[k] == (k+1)-th LARGEST dot.
//  1) normalize_bf16: fused z+ref rows -> L2-normalized bf16
//  2) knn_pass<1>:  MFMA dots, epilogue = per-(row,chunk,lane16) subset MAX
//  3) knn_threshold: per row, exact 11th-largest of 1024 subset maxes -> T
//  4) knn_pass<2>:  MFMA dots again, keep v >= T[row] via atomic append
//  5) knn_final: exact 11th-largest of survivors -> dist
//
// Round-5 change (single variable): occupancy at the SPILL-FREE point.
// Round-4's __launch_bounds__(256,5) squeezed VGPR 68->48 and spilled
// (WRITE_SIZE 1.2->39.7 MB = scratch traffic, MfmaUtil 21->12%, pass 45->83us).
// This round: __launch_bounds__(256,4) (VGPR cap 128 >> our 68, no squeeze),
// NCH=64 -> grid 16x64=1024 blocks = exactly 4/CU; LDS 4x32KB=128KB fits;
// VGPR 68 permits 16 waves/CU (m69) so 4 blocks/CU is the natural ceiling.
//  - 1024%8==0 -> bijective XCD swizzle; per-XCD refs 8x782x256B=1.6MB L2-fit.
//  - NSUB=1024; threshold does 16 sorted-insert rounds.
//  - knn_pass body is the round-3 known-good (VGPR 68, 0 bank conflicts):
//    gld_lds width-16, double-buffer, counted vmcnt(4), XOR slot swizzle via
//    pre-swizzled global source, setprio around the MFMA cluster.
//
// Accuracy: bf16 rounding perturbs each dot by ~3.5e-4; k-th order statistic
// is 1-Lipschitz in that perturbation -> << 2.39e-2 threshold.  Threshold
// bound: a subset max > v11 (true 11th-largest) implies the subset holds a
// top-10 dot -> at most 10 such subsets -> T (11th-largest subset max) <= v11,
// so all top-11 dots survive the v >= T filter.

#define D_DIM 128
#define TQ 128         // queries per block (4 waves x 2 row-tiles x 16 rows)
#define BR 64          // refs per block iteration
#define NCH 64         // ref chunks; grid 16*64=1024 blocks = 4/CU; 1024%8==0
#define NSUB (NCH * 16) // subsets per row = 1024
#define KK 11          // need 11th largest (k=10); selection slots
#define CAP 256        // survivor capacity per row

typedef __bf16 bf16_t;
typedef bf16_t bf16x8 __attribute__((ext_vector_type(8)));
typedef float f32x4 __attribute__((ext_vector_type(4)));

__device__ __forceinline__ unsigned short f2bf(float f) {
    unsigned u = __float_as_uint(f);
    return (unsigned short)((u + 0x7fffu + ((u >> 16) & 1u)) >> 16);  // RNE
}

__global__ __launch_bounds__(256) void normalize_bf16(
    const float* __restrict__ z, const float* __restrict__ ref,
    unsigned short* __restrict__ zb, unsigned short* __restrict__ rb,
    int N, int M)
{
    const int w = threadIdx.x >> 6;
    const int l = threadIdx.x & 63;
    const int row = blockIdx.x * 4 + w;
    if (row >= N + M) return;
    const float* in; unsigned short* out; int r;
    if (row < N) { in = z;   out = zb; r = row; }
    else         { in = ref; out = rb; r = row - N; }
    const float2 v = ((const float2*)in)[(size_t)r * 64 + l];
    float ss = v.x * v.x + v.y * v.y;
    #pragma unroll
    for (int off = 32; off > 0; off >>= 1) ss += __shfl_xor(ss, off);
    const float inv = rsqrtf(ss);
    ushort2 o; o.x = f2bf(v.x * inv); o.y = f2bf(v.y * inv);
    ((ushort2*)out)[(size_t)r * 64 + l] = o;
}

// async global->LDS, 16B per lane; LDS dest is wave-uniform base + lane*16.
__device__ __forceinline__ void gld_lds16(const unsigned short* g,
                                          unsigned short* l) {
    __builtin_amdgcn_global_load_lds(
        (__attribute__((address_space(1))) void*)g,
        (__attribute__((address_space(3))) void*)l, 16, 0, 0);
}

// PASS==1: write subset maxes.  PASS==2: filter vs T, append survivors.
template <int PASS>
__global__ __launch_bounds__(256, 4) void knn_pass(
    const unsigned short* __restrict__ zb, const unsigned short* __restrict__ rb,
    float* __restrict__ maxes, const float* __restrict__ T,
    int* __restrict__ cnt, float* __restrict__ surv,
    int N, int M, int chunk)
{
    // Double-buffered B tile: 2 x 64 rows x 128 bf16 (256B/row, no pad;
    // bank spread comes from the XOR slot swizzle).  32 KiB total.
    __shared__ __align__(16) unsigned short Bt[2 * BR * D_DIM];

    // T1 XCD swizzle: dispatch round-robins linear bid over 8 XCDs.  Remap so
    // XCD k owns ref-chunks [8k, 8k+8) exclusively (1.6 MB, L2-fit).
    const int nbx = (int)gridDim.x;                       // 16
    const int nwg = nbx * (int)gridDim.y;                 // 1024, %8 == 0
    const int bid = (int)blockIdx.x + nbx * (int)blockIdx.y;
    const int swz = (bid & 7) * (nwg >> 3) + (bid >> 3);
    const int bx = swz % nbx;
    const int by = swz / nbx;

    const int t = threadIdx.x;
    const int lane = t & 63;
    const int w = t >> 6;          // wave -> query rows w*32 .. w*32+31
    const int quad = lane >> 4;
    const int ln = lane & 15;
    const int qbase = bx * TQ;
    const int c0 = by * chunk;
    const int c1 = min(c0 + chunk, M);
    const int nt = (c1 - c0 + BR - 1) / BR;   // block-uniform (13 here)

    // A fragments straight from global: rows w*32 + rt*16 + ln, loop-invariant.
    // zb is 0.5 MB -> L2-resident; one-time cost.
    bf16x8 afr[2][4];
    #pragma unroll
    for (int rt = 0; rt < 2; ++rt)
        #pragma unroll
        for (int ks = 0; ks < 4; ++ks)
            afr[rt][ks] = *(const bf16x8*)
                &zb[(size_t)(qbase + w * 32 + rt * 16 + ln) * D_DIM
                    + ks * 32 + quad * 8];

    float mx[2][4];   // pass1: per-lane subset max, rows rt*16+quad*4+r
    float tr[2][4];   // pass2: per-row thresholds
    if (PASS == 1) {
        #pragma unroll
        for (int rt = 0; rt < 2; ++rt)
            #pragma unroll
            for (int r = 0; r < 4; ++r) mx[rt][r] = -3.0f;
    } else {
        #pragma unroll
        for (int rt = 0; rt < 2; ++rt)
            #pragma unroll
            for (int r = 0; r < 4; ++r)
                tr[rt][r] = T[qbase + w * 32 + rt * 16 + quad * 4 + r];
    }

    // Stage one 64-row tile into LDS half `half`.  Per wave: 4 glds calls,
    // each 4 rows (64 lanes x 16B = 1KB, linear dest).  Source slot is
    // pre-swizzled so LDS row r physical slot p holds logical slot p^(r&15).
    auto stage = [&](int half, int tile) {
        const int s0 = c0 + tile * BR;
        #pragma unroll
        for (int i = 0; i < 4; ++i) {
            const int r = w * 16 + i * 4 + quad;        // lane's source row
            int g = s0 + r; if (g > M - 1) g = M - 1;   // clamp; excluded below
            const int sl = ln ^ (r & 15);               // inverse-swizzled slot
            gld_lds16(&rb[(size_t)g * D_DIM + sl * 8],
                      &Bt[half * (BR * D_DIM) + (w * 16 + i * 4) * D_DIM]);
        }
    };

    stage(0, 0);
    stage(1, nt > 1 ? 1 : 0);

    for (int it = 0; it < nt; ++it) {
        // Wait only for THIS tile's 4 stage loads (tile it+1's 4 stay in
        // flight).  Last iteration has no younger stage group -> drain.
        if (it + 1 < nt) asm volatile("s_waitcnt vmcnt(4)" ::: "memory");
        else             asm volatile("s_waitcnt vmcnt(0)" ::: "memory");
        __builtin_amdgcn_s_barrier();
        asm volatile("" ::: "memory");        // no LDS reads hoisted above
        __builtin_amdgcn_sched_barrier(0);

        const int cur = it & 1;
        const int s0 = c0 + it * BR;
        const unsigned short* Bc = &Bt[cur * (BR * D_DIM)];

        f32x4 acc[2][4];
        #pragma unroll
        for (int rt = 0; rt < 2; ++rt)
            #pragma unroll
            for (int ct = 0; ct < 4; ++ct) acc[rt][ct] = (f32x4){0.f,0.f,0.f,0.f};

        __builtin_amdgcn_s_setprio(1);
        #pragma unroll
        for (int ks = 0; ks < 4; ++ks) {
            #pragma unroll
            for (int ct = 0; ct < 4; ++ct) {
                const int r = ct * 16 + ln;
                bf16x8 bfr = *(const bf16x8*)
                    &Bc[r * D_DIM + ((ks * 4 + quad) ^ ln) * 8];  // swizzled read
                #pragma unroll
                for (int rt = 0; rt < 2; ++rt)
                    acc[rt][ct] = __builtin_amdgcn_mfma_f32_16x16x32_bf16(
                        afr[rt][ks], bfr, acc[rt][ct], 0, 0, 0);
            }
        }
        __builtin_amdgcn_s_setprio(0);

        // Epilogue. Lane's column g is uniform across rt/r for fixed ct.
        #pragma unroll
        for (int ct = 0; ct < 4; ++ct) {
            int g = s0 + ct * 16 + ln;
            if (g < c1) {
                if (PASS == 1) {
                    #pragma unroll
                    for (int rt = 0; rt < 2; ++rt)
                        #pragma unroll
                        for (int r = 0; r < 4; ++r)
                            mx[rt][r] = fmaxf(mx[rt][r], acc[rt][ct][r]);
                } else {
                    #pragma unroll
                    for (int rt = 0; rt < 2; ++rt)
                        #pragma unroll
                        for (int r = 0; r < 4; ++r) {
                            float v = acc[rt][ct][r];
                            if (v >= tr[rt][r]) {   // rare
                                int row = qbase + w * 32 + rt * 16 + quad * 4 + r;
                                int slot = atomicAdd(&cnt[row], 1);
                                if (slot < CAP) surv[(size_t)row * CAP + slot] = v;
                            }
                        }
                }
            }
        }

        __builtin_amdgcn_sched_barrier(0);
        asm volatile("" ::: "memory");        // no LDS reads sunk below
        __builtin_amdgcn_s_barrier();          // all waves done reading buf[cur]
        if (it + 2 < nt) stage(cur, it + 2);   // refill the buffer just read
    }

    if (PASS == 1) {
        #pragma unroll
        for (int rt = 0; rt < 2; ++rt)
            #pragma unroll
            for (int r = 0; r < 4; ++r) {
                int row = qbase + w * 32 + rt * 16 + quad * 4 + r;
                maxes[(size_t)row * NSUB + by * 16 + ln] = mx[rt][r];
            }
    }
}

// Per-lane sorted top-(KK) slots, then kk+1 global max-extractions with
// static-shift pop (rule #20: no dynamic register indexing).
__device__ __forceinline__ float kth_largest_64(float* s, int kk, int t) {
    float cur = -3.0f;
    for (int it = 0; it <= kk; ++it) {
        float m = s[0];
        #pragma unroll
        for (int off = 32; off > 0; off >>= 1) m = fmaxf(m, __shfl_xor(m, off));
        cur = m;
        unsigned long long b = __ballot(s[0] == m);
        bool owner = ((int)(__ffsll(b) - 1) == t);
        #pragma unroll
        for (int j = 0; j < KK - 1; ++j) s[j] = owner ? s[j + 1] : s[j];
        if (owner) s[KK - 1] = -3.0f;
    }
    return cur;
}

__global__ __launch_bounds__(64) void knn_threshold(
    const float* __restrict__ maxes, const int* __restrict__ kp,
    float* __restrict__ T, int* __restrict__ cnt)
{
    const int row = blockIdx.x;
    const int t = threadIdx.x;
    float s[KK];
    #pragma unroll
    for (int j = 0; j < KK; ++j) s[j] = -3.0f;
    #pragma unroll
    for (int i = 0; i < NSUB / 64; ++i) {     // 16 coalesced loads
        float v = maxes[(size_t)row * NSUB + t + 64 * i];
        #pragma unroll
        for (int j = 0; j < KK; ++j) {        // descending sorted insert
            float hi = fmaxf(s[j], v), lo = fminf(s[j], v);
            s[j] = hi; v = lo;
        }
    }
    const int kk = *kp;   // 10
    float cur = kth_largest_64(s, kk, t);
    if (t == 0) { T[row] = cur; cnt[row] = 0; }
}

__global__ __launch_bounds__(64) void knn_final(
    const float* __restrict__ surv, const int* __restrict__ cnt,
    const int* __restrict__ kp, float* __restrict__ out)
{
    const int row = blockIdx.x;
    const int t = threadIdx.x;
    int c = cnt[row]; if (c > CAP) c = CAP;
    float s[KK];
    #pragma unroll
    for (int j = 0; j < KK; ++j) s[j] = -3.0f;
    #pragma unroll
    for (int i = 0; i < CAP / 64; ++i) {      // 4 coalesced loads
        int idx = t + 64 * i;
        float v = (idx < c) ? surv[(size_t)row * CAP + idx] : -3.0f;
        #pragma unroll
        for (int j = 0; j < KK; ++j) {
            float hi = fmaxf(s[j], v), lo = fminf(s[j], v);
            s[j] = hi; v = lo;
        }
    }
    const int kk = *kp;
    float cur = kth_largest_64(s, kk, t);
    if (t == 0) out[row] = sqrtf(fmaxf(2.0f - 2.0f * cur, 1e-12f));
}

extern "C" void kernel_launch(void* const* d_in, const int* in_sizes, int n_in,
                              void* d_out, int out_size, void* d_ws, size_t ws_size,
                              hipStream_t stream) {
    const float* z   = (const float*)d_in[0];
    const float* ref = (const float*)d_in[1];
    const int*   kp  = (const int*)d_in[2];
    float* out = (float*)d_out;

    const int N = in_sizes[0] / D_DIM;   // 2048
    const int M = in_sizes[1] / D_DIM;   // 50000

    unsigned short* zbuf = (unsigned short*)d_ws;             // N*128 bf16
    unsigned short* rbuf = zbuf + (size_t)N * D_DIM;          // M*128 bf16
    float* maxes = (float*)(rbuf + (size_t)M * D_DIM);        // N*NSUB f32 (8MB)
    float* T     = maxes + (size_t)N * NSUB;                  // N f32
    int*   cnt   = (int*)(T + N);                             // N i32
    float* surv  = (float*)(cnt + N);                         // N*CAP f32 (2MB)

    normalize_bf16<<<(N + M + 3) / 4, 256, 0, stream>>>(z, ref, zbuf, rbuf, N, M);

    const int chunk = (M + NCH - 1) / NCH;    // 782
    dim3 grid(N / TQ, NCH);                   // 16 x 64 = 1024 blocks, 4/CU

    knn_pass<1><<<grid, 256, 0, stream>>>(zbuf, rbuf, maxes, nullptr,
                                          nullptr, nullptr, N, M, chunk);
    knn_threshold<<<N, 64, 0, stream>>>(maxes, kp, T, cnt);
    knn_pass<2><<<grid, 256, 0, stream>>>(zbuf, rbuf, nullptr, T,
                                          cnt, surv, N, M, chunk);
    knn_final<<<N, 64, 0, stream>>>(surv, cnt, kp, out);
}